// Round 12
// baseline (140.650 us; speedup 1.0000x reference)
//
#include <hip/hip_runtime.h>
#include <stdint.h>
#include <stddef.h>

#define BATCH 64
#define NN    1024
#define DD    64            // DIN == DOUT == 64
#define XWB   512           // xw blocks at the head of the merged grid (dispatch first)
#define DEGB  (BATCH * NN / 4)

typedef _Float16 h8 __attribute__((ext_vector_type(8)));
typedef _Float16 h4 __attribute__((ext_vector_type(4)));
typedef float    f32x4 __attribute__((ext_vector_type(4)));

// XOR-swizzled granule slot: [rows][8 granules of 16B] tiles.
__device__ __forceinline__ int swz(int row, int gran) {
    return (row << 3) + (gran ^ (row & 7));
}

// ---------------- K1: heterogeneous deg + xw (+ weight passthrough) --------------------
// Blocks [0, XWB): zT[b][d][j] = (att @ W)[j][d] fp16 UNscaled; block 0 copies weight.
// Blocks [XWB, XWB+DEGB): row-degree streams, 1 row/wave -> dinv. (r10 verbatim;
// fp16 adj transcode measured SLOWER twice (r1->r2, r10->r11) -- do not reintroduce.)
__global__ __launch_bounds__(256) void k_degxw(const float* __restrict__ adj,
                                               const float* __restrict__ att,
                                               const float* __restrict__ wgt,
                                               _Float16* __restrict__ zT,
                                               float* __restrict__ dinv,
                                               float* __restrict__ ow) {
    __shared__ __align__(16) _Float16 attS[128 * 64];
    __shared__ __align__(16) _Float16 wtS[64 * 64];
    const int t = threadIdx.x;
    const int x = blockIdx.x;

    if (x >= XWB) {
        // ---- deg branch: one row per wave ----
        const int lane = t & 63;
        const int rowg = (x - XWB) * 4 + (t >> 6);
        const float* rp = adj + (size_t)rowg * NN;
        float s = 0.f;
#pragma unroll
        for (int k = 0; k < 4; ++k) {
            const float4 v = ((const float4*)rp)[lane + (k << 6)];
            s += v.x + v.y + v.z + v.w;
        }
#pragma unroll
        for (int off = 32; off; off >>= 1) s += __shfl_xor(s, off);
        if (lane == 0) dinv[rowg] = 1.f / sqrtf(s);
        return;
    }

    // ---- xw branch: batch bb, 128-row j-tile ----
    const int bb = x >> 3;
    const int j0 = (x & 7) * 128;
    if (x == 0) {                                    // tuple output #1: weight copy
#pragma unroll
        for (int it = 0; it < 4; ++it) {
            const int idx = t + (it << 8);
            ((float4*)ow)[idx] = ((const float4*)wgt)[idx];
        }
    }
    // stage att tile (fp32 -> fp16)
#pragma unroll
    for (int it = 0; it < 4; ++it) {
        const int g = t + (it << 8);
        const int r = g >> 3, c = g & 7;
        const float4* p = (const float4*)(att + (size_t)(bb * NN + j0 + r) * DD + (c << 3));
        const float4 v0 = p[0], v1 = p[1];
        h8 o;
        o[0] = (_Float16)v0.x; o[1] = (_Float16)v0.y; o[2] = (_Float16)v0.z; o[3] = (_Float16)v0.w;
        o[4] = (_Float16)v1.x; o[5] = (_Float16)v1.y; o[6] = (_Float16)v1.z; o[7] = (_Float16)v1.w;
        *(h8*)&attS[swz(r, c) * 8] = o;
    }
    // stage W^T (fp32 w[k][d] -> wtS[d][k] fp16)
#pragma unroll
    for (int it = 0; it < 4; ++it) {
        const int idx = t + (it << 8);               // float4 id 0..1023
        const int k = idx >> 4, d4 = (idx & 15) << 2;
        const float4 v = ((const float4*)wgt)[idx];
        wtS[swz(d4 + 0, k >> 3) * 8 + (k & 7)] = (_Float16)v.x;
        wtS[swz(d4 + 1, k >> 3) * 8 + (k & 7)] = (_Float16)v.y;
        wtS[swz(d4 + 2, k >> 3) * 8 + (k & 7)] = (_Float16)v.z;
        wtS[swz(d4 + 3, k >> 3) * 8 + (k & 7)] = (_Float16)v.w;
    }
    __syncthreads();

    const int w = t >> 6, lane = t & 63;
    const int lr = lane & 15, lg = lane >> 4;
    const f32x4 zero = {0.f, 0.f, 0.f, 0.f};
    f32x4 acc[2][4];
#pragma unroll
    for (int mf = 0; mf < 2; ++mf)
#pragma unroll
        for (int nf = 0; nf < 4; ++nf) acc[mf][nf] = zero;

#pragma unroll
    for (int kk = 0; kk < 2; ++kk) {
        h8 a[2], bfr[4];
#pragma unroll
        for (int mf = 0; mf < 2; ++mf)
            a[mf] = *(const h8*)&attS[swz(w * 32 + mf * 16 + lr, kk * 4 + lg) * 8];
#pragma unroll
        for (int nf = 0; nf < 4; ++nf)
            bfr[nf] = *(const h8*)&wtS[swz(nf * 16 + lr, kk * 4 + lg) * 8];
#pragma unroll
        for (int mf = 0; mf < 2; ++mf)
#pragma unroll
            for (int nf = 0; nf < 4; ++nf)
                acc[mf][nf] = __builtin_amdgcn_mfma_f32_16x16x32_f16(a[mf], bfr[nf], acc[mf][nf], 0, 0, 0);
    }

    // D layout: col(d)=lane&15, row(j)=(lane>>4)*4+reg -> 4 consecutive j -> 8B store.
#pragma unroll
    for (int mf = 0; mf < 2; ++mf) {
        const int jb = j0 + w * 32 + mf * 16 + lg * 4;
#pragma unroll
        for (int nf = 0; nf < 4; ++nf) {
            const int d = nf * 16 + lr;
            h4 o;
            o[0] = (_Float16)acc[mf][nf][0];
            o[1] = (_Float16)acc[mf][nf][1];
            o[2] = (_Float16)acc[mf][nf][2];
            o[3] = (_Float16)acc[mf][nf][3];
            *(h4*)(zT + (size_t)(bb * DD + d) * NN + jb) = o;
        }
    }
}

// Barrier that does NOT drain vmcnt: prefetch global loads stay in flight (T4).
#define BARNV() do {                                          \
    __builtin_amdgcn_sched_barrier(0);                        \
    asm volatile("s_waitcnt lgkmcnt(0)" ::: "memory");        \
    __builtin_amdgcn_s_barrier();                             \
    __builtin_amdgcn_sched_barrier(0);                        \
} while (0)

// Prefetch one 64x64 adj tile into named registers (4 fp32x4 loads, stay in flight).
#define LOADT(P, kt) do {                                                             \
    const int gj = (kt) * 64 + (c0 << 3);                                             \
    const f32x4* p0_ = (const f32x4*)(adj + (size_t)(bb * NN + i0 + r0) * NN + gj);   \
    P##a00 = p0_[0]; P##a01 = p0_[1];                                                 \
    const f32x4* p1_ = (const f32x4*)(adj + (size_t)(bb * NN + i0 + r1) * NN + gj);   \
    P##a10 = p1_[0]; P##a11 = p1_[1];                                                 \
} while (0)

// Stage prefetched tile: A = (fp16)(adj_ij * dinv_j). dinv_j folded here (B is raw z).
#define WRITET(P, kt, A_) do {                                                        \
    const int gj = (kt) * 64 + (c0 << 3);                                             \
    const f32x4 d0_ = *(const f32x4*)(dvB + gj);                                      \
    const f32x4 d1_ = *(const f32x4*)(dvB + gj + 4);                                  \
    h8 a0_, a1_;                                                                      \
    _Pragma("unroll") for (int e = 0; e < 4; ++e) {                                   \
        a0_[e]     = (_Float16)(P##a00[e] * d0_[e]);                                  \
        a0_[4 + e] = (_Float16)(P##a01[e] * d1_[e]);                                  \
        a1_[e]     = (_Float16)(P##a10[e] * d0_[e]);                                  \
        a1_[4 + e] = (_Float16)(P##a11[e] * d1_[e]);                                  \
    }                                                                                 \
    *(h8*)&(A_)[swz(r0, c0) * 8] = a0_;                                               \
    *(h8*)&(A_)[swz(r1, c0) * 8] = a1_;                                               \
} while (0)

// MFMA over one tile: A from LDS, B straight from global zT (L2-resident; addressing
// lifted verbatim from the r4-6 correctness-proven fused AGG).
#define MMAT(A_, kt) do {                                                             \
    _Pragma("unroll") for (int kk = 0; kk < 2; ++kk) {                                \
        const h8 a_ = *(const h8*)&(A_)[swz(w * 16 + lr, kk * 4 + lg) * 8];           \
        _Pragma("unroll") for (int nf = 0; nf < 4; ++nf) {                            \
            const h8 bz_ = *(const h8*)(zTr + (size_t)(nf * 16) * NN                  \
                                        + (kt) * 64 + (kk * 4 + lg) * 8);             \
            acc[nf] = __builtin_amdgcn_mfma_f32_16x16x32_f16(a_, bz_, acc[nf], 0, 0, 0); \
        }                                                                             \
    }                                                                                 \
} while (0)

// ---------------- K2: out[b][i][d] = dinv_i * (sum_j adj_ij * dinv_j * z[j][d] + dinv_i*z[i][d])
// Pure streaming (adj fp32 from HBM). Depth-2 named-reg prefetch, dbuf LDS (A only,
// 16 KiB -> 6 blocks/CU), one non-draining barrier per tile, B direct from L2 zT.
// Self-loop in epilogue. Bijective XCD-chunked swizzle (8 whole batches per XCD).
__global__ __launch_bounds__(256, 6) void k_agg(const float* __restrict__ adj,
                                                const _Float16* __restrict__ zT,
                                                const float* __restrict__ dinv,
                                                float* __restrict__ out) {
    __shared__ __align__(16) _Float16 SA0[64 * 64], SA1[64 * 64];
    const int t = threadIdx.x;
    const int wg = (blockIdx.x & 7) * 128 + (blockIdx.x >> 3);   // bijective: 1024 = 8*128
    const int bb = wg >> 4;
    const int i0 = (wg & 15) << 6;
    const int w = t >> 6, lane = t & 63;
    const int lr = lane & 15, lg = lane >> 4;
    const float* dvB = dinv + bb * NN;
    const _Float16* zTr = zT + ((size_t)bb * DD + lr) * NN;      // B base: d-row = nf*16+lr
    const int r0 = t >> 3, c0 = t & 7;               // staging rows 0..31
    const int r1 = 32 + (t >> 3);                    // staging rows 32..63

    f32x4 Aa00, Aa01, Aa10, Aa11;                    // named prefetch set A
    f32x4 Ba00, Ba01, Ba10, Ba11;                    // named prefetch set B

    const f32x4 zero = {0.f, 0.f, 0.f, 0.f};
    f32x4 acc[4];
#pragma unroll
    for (int nf = 0; nf < 4; ++nf) acc[nf] = zero;

    LOADT(A, 0);
    LOADT(B, 1);
    WRITET(A, 0, SA0);
    BARNV();
#pragma unroll 1
    for (int kt = 0; kt < 16; kt += 2) {
        if (kt + 2 < 16) LOADT(A, kt + 2);           // in flight across barriers
        MMAT(SA0, kt);                               // tile kt
        WRITET(B, kt + 1, SA1);
        BARNV();
        if (kt + 3 < 16) LOADT(B, kt + 3);
        MMAT(SA1, kt + 1);                           // tile kt+1
        if (kt + 2 < 16) WRITET(A, kt + 2, SA0);
        BARNV();
    }

    // epilogue: out = dinv_i * (acc + dinv_i * z_i[d]); 4 consecutive output rows.
    const int ib = i0 + w * 16 + lg * 4;
    const float4 dv = *(const float4*)&dvB[ib];
#pragma unroll
    for (int nf = 0; nf < 4; ++nf) {
        const int d = nf * 16 + lr;
        const h4 zv = *(const h4*)(zT + ((size_t)bb * DD + d) * NN + ib);
        float* op = out + ((size_t)bb * NN + ib) * DD + d;
        __builtin_nontemporal_store(dv.x * (acc[nf][0] + dv.x * (float)zv[0]), op + 0 * DD);
        __builtin_nontemporal_store(dv.y * (acc[nf][1] + dv.y * (float)zv[1]), op + 1 * DD);
        __builtin_nontemporal_store(dv.z * (acc[nf][2] + dv.z * (float)zv[2]), op + 2 * DD);
        __builtin_nontemporal_store(dv.w * (acc[nf][3] + dv.w * (float)zv[3]), op + 3 * DD);
    }
}

extern "C" void kernel_launch(void* const* d_in, const int* in_sizes, int n_in,
                              void* d_out, int out_size, void* d_ws, size_t ws_size,
                              hipStream_t stream) {
    const float* adj = (const float*)d_in[0];
    const float* att = (const float*)d_in[1];
    const float* wgt = (const float*)d_in[2];
    float* out = (float*)d_out;
    char* ws = (char*)d_ws;

    size_t off = 0;
    _Float16* zT  = (_Float16*)(ws + off); off += (size_t)BATCH * DD * NN * 2;  // 8 MiB
    float*    dinv = (float*)(ws + off);                                        // 256 KiB

    k_degxw<<<XWB + DEGB, 256, 0, stream>>>(adj, att, wgt, zT, dinv,
                                            out + (size_t)BATCH * NN * DD);
    k_agg<<<BATCH * (NN / 64), 256, 0, stream>>>(adj, zT, dinv, out);
}

// Round 13
// 102.558 us; speedup vs baseline: 1.3714x; 1.3714x over previous
//
#include <hip/hip_runtime.h>
#include <stdint.h>
#include <stddef.h>

#define BATCH 64
#define NN    1024
#define DD    64            // DIN == DOUT == 64
#define XWB   512           // xw blocks at the head of the merged grid (dispatch first)
#define DEGB  (BATCH * NN / 4)

typedef _Float16 h8 __attribute__((ext_vector_type(8)));
typedef _Float16 h4 __attribute__((ext_vector_type(4)));
typedef float    f32x4 __attribute__((ext_vector_type(4)));

// XOR-swizzled granule slot: [rows][8 granules of 16B] tiles.
__device__ __forceinline__ int swz(int row, int gran) {
    return (row << 3) + (gran ^ (row & 7));
}

// ---------------- K1: heterogeneous deg + xw (+ weight passthrough) --------------------
// Blocks [0, XWB): zT[b][d][j] = (att @ W)[j][d] fp16 UNscaled; block 0 copies weight.
// Blocks [XWB, XWB+DEGB): row-degree streams, 1 row/wave -> dinv.
// MEASURED dead ends (do not reintroduce): adj fp16 transcode (r11, r2: write
// round-trip > read savings); L3-reuse / read-once sync designs (r5-r9: 2-8x slower);
// direct-global-B MFMA operands (r12: vmcnt ordering drains the counted prefetch).
__global__ __launch_bounds__(256) void k_degxw(const float* __restrict__ adj,
                                               const float* __restrict__ att,
                                               const float* __restrict__ wgt,
                                               _Float16* __restrict__ zT,
                                               float* __restrict__ dinv,
                                               float* __restrict__ ow) {
    __shared__ __align__(16) _Float16 attS[128 * 64];
    __shared__ __align__(16) _Float16 wtS[64 * 64];
    const int t = threadIdx.x;
    const int x = blockIdx.x;

    if (x >= XWB) {
        // ---- deg branch: one row per wave ----
        const int lane = t & 63;
        const int rowg = (x - XWB) * 4 + (t >> 6);
        const float* rp = adj + (size_t)rowg * NN;
        float s = 0.f;
#pragma unroll
        for (int k = 0; k < 4; ++k) {
            const float4 v = ((const float4*)rp)[lane + (k << 6)];
            s += v.x + v.y + v.z + v.w;
        }
#pragma unroll
        for (int off = 32; off; off >>= 1) s += __shfl_xor(s, off);
        if (lane == 0) dinv[rowg] = 1.f / sqrtf(s);
        return;
    }

    // ---- xw branch: batch bb, 128-row j-tile ----
    const int bb = x >> 3;
    const int j0 = (x & 7) * 128;
    if (x == 0) {                                    // tuple output #1: weight copy
#pragma unroll
        for (int it = 0; it < 4; ++it) {
            const int idx = t + (it << 8);
            ((float4*)ow)[idx] = ((const float4*)wgt)[idx];
        }
    }
    // stage att tile (fp32 -> fp16)
#pragma unroll
    for (int it = 0; it < 4; ++it) {
        const int g = t + (it << 8);
        const int r = g >> 3, c = g & 7;
        const float4* p = (const float4*)(att + (size_t)(bb * NN + j0 + r) * DD + (c << 3));
        const float4 v0 = p[0], v1 = p[1];
        h8 o;
        o[0] = (_Float16)v0.x; o[1] = (_Float16)v0.y; o[2] = (_Float16)v0.z; o[3] = (_Float16)v0.w;
        o[4] = (_Float16)v1.x; o[5] = (_Float16)v1.y; o[6] = (_Float16)v1.z; o[7] = (_Float16)v1.w;
        *(h8*)&attS[swz(r, c) * 8] = o;
    }
    // stage W^T (fp32 w[k][d] -> wtS[d][k] fp16)
#pragma unroll
    for (int it = 0; it < 4; ++it) {
        const int idx = t + (it << 8);               // float4 id 0..1023
        const int k = idx >> 4, d4 = (idx & 15) << 2;
        const float4 v = ((const float4*)wgt)[idx];
        wtS[swz(d4 + 0, k >> 3) * 8 + (k & 7)] = (_Float16)v.x;
        wtS[swz(d4 + 1, k >> 3) * 8 + (k & 7)] = (_Float16)v.y;
        wtS[swz(d4 + 2, k >> 3) * 8 + (k & 7)] = (_Float16)v.z;
        wtS[swz(d4 + 3, k >> 3) * 8 + (k & 7)] = (_Float16)v.w;
    }
    __syncthreads();

    const int w = t >> 6, lane = t & 63;
    const int lr = lane & 15, lg = lane >> 4;
    const f32x4 zero = {0.f, 0.f, 0.f, 0.f};
    f32x4 acc[2][4];
#pragma unroll
    for (int mf = 0; mf < 2; ++mf)
#pragma unroll
        for (int nf = 0; nf < 4; ++nf) acc[mf][nf] = zero;

#pragma unroll
    for (int kk = 0; kk < 2; ++kk) {
        h8 a[2], bfr[4];
#pragma unroll
        for (int mf = 0; mf < 2; ++mf)
            a[mf] = *(const h8*)&attS[swz(w * 32 + mf * 16 + lr, kk * 4 + lg) * 8];
#pragma unroll
        for (int nf = 0; nf < 4; ++nf)
            bfr[nf] = *(const h8*)&wtS[swz(nf * 16 + lr, kk * 4 + lg) * 8];
#pragma unroll
        for (int mf = 0; mf < 2; ++mf)
#pragma unroll
            for (int nf = 0; nf < 4; ++nf)
                acc[mf][nf] = __builtin_amdgcn_mfma_f32_16x16x32_f16(a[mf], bfr[nf], acc[mf][nf], 0, 0, 0);
    }

    // D layout: col(d)=lane&15, row(j)=(lane>>4)*4+reg -> 4 consecutive j -> 8B store.
#pragma unroll
    for (int mf = 0; mf < 2; ++mf) {
        const int jb = j0 + w * 32 + mf * 16 + lg * 4;
#pragma unroll
        for (int nf = 0; nf < 4; ++nf) {
            const int d = nf * 16 + lr;
            h4 o;
            o[0] = (_Float16)acc[mf][nf][0];
            o[1] = (_Float16)acc[mf][nf][1];
            o[2] = (_Float16)acc[mf][nf][2];
            o[3] = (_Float16)acc[mf][nf][3];
            *(h4*)(zT + (size_t)(bb * DD + d) * NN + jb) = o;
        }
    }
}

// Barrier that does NOT drain vmcnt: prefetch global loads stay in flight (T4).
#define BARNV() do {                                          \
    __builtin_amdgcn_sched_barrier(0);                        \
    asm volatile("s_waitcnt lgkmcnt(0)" ::: "memory");        \
    __builtin_amdgcn_s_barrier();                             \
    __builtin_amdgcn_sched_barrier(0);                        \
} while (0)

// Prefetch one 64x64 tile into named registers (6 global loads, stay in flight).
#define LOADT(P, kt) do {                                                             \
    const int gj = (kt) * 64 + (c0 << 3);                                             \
    const f32x4* p0_ = (const f32x4*)(adj + (size_t)(bb * NN + i0 + r0) * NN + gj);   \
    P##a00 = p0_[0]; P##a01 = p0_[1];                                                 \
    const f32x4* p1_ = (const f32x4*)(adj + (size_t)(bb * NN + i0 + r1) * NN + gj);   \
    P##a10 = p1_[0]; P##a11 = p1_[1];                                                 \
    P##z0 = *(const h8*)(zT + (size_t)(bb * DD + r0) * NN + gj);                      \
    P##z1 = *(const h8*)(zT + (size_t)(bb * DD + r1) * NN + gj);                      \
} while (0)

// Stage prefetched tile: A = raw adj fp16 (no diag, no scale); Z = dinv_j * z.
#define WRITET(P, kt, A_, Z_) do {                                                    \
    const int gj = (kt) * 64 + (c0 << 3);                                             \
    const f32x4 d0_ = *(const f32x4*)(dvB + gj);                                      \
    const f32x4 d1_ = *(const f32x4*)(dvB + gj + 4);                                  \
    h8 a0_, a1_, z0_, z1_;                                                            \
    _Pragma("unroll") for (int e = 0; e < 4; ++e) {                                   \
        a0_[e]     = (_Float16)P##a00[e];                                             \
        a0_[4 + e] = (_Float16)P##a01[e];                                             \
        a1_[e]     = (_Float16)P##a10[e];                                             \
        a1_[4 + e] = (_Float16)P##a11[e];                                             \
        z0_[e]     = (_Float16)((float)P##z0[e]     * d0_[e]);                        \
        z0_[4 + e] = (_Float16)((float)P##z0[4 + e] * d1_[e]);                        \
        z1_[e]     = (_Float16)((float)P##z1[e]     * d0_[e]);                        \
        z1_[4 + e] = (_Float16)((float)P##z1[4 + e] * d1_[e]);                        \
    }                                                                                 \
    *(h8*)&(A_)[swz(r0, c0) * 8] = a0_;                                               \
    *(h8*)&(A_)[swz(r1, c0) * 8] = a1_;                                               \
    *(h8*)&(Z_)[swz(r0, c0) * 8] = z0_;                                               \
    *(h8*)&(Z_)[swz(r1, c0) * 8] = z1_;                                               \
} while (0)

#define MMAT(A_, Z_) do {                                                             \
    _Pragma("unroll") for (int kk = 0; kk < 2; ++kk) {                                \
        const h8 a_ = *(const h8*)&(A_)[swz(w * 16 + lr, kk * 4 + lg) * 8];           \
        _Pragma("unroll") for (int nf = 0; nf < 4; ++nf) {                            \
            const h8 bz_ = *(const h8*)&(Z_)[swz(nf * 16 + lr, kk * 4 + lg) * 8];     \
            acc[nf] = __builtin_amdgcn_mfma_f32_16x16x32_f16(a_, bz_, acc[nf], 0, 0, 0); \
        }                                                                             \
    }                                                                                 \
} while (0)

// ---------------- K2: out[b][i][d] = dinv_i * (sum_j adj_ij * dinv_j * z[j][d] + dinv_i*z[i][d])
// Pure streaming (adj re-read from HBM -- measured FASTER than all L3-reuse designs).
// Depth-2 named-reg prefetch, double-buffered LDS, one non-draining barrier per tile.
// Self-loop handled in the epilogue: no diag fixup, no dinv-A traffic in the loop.
__global__ __launch_bounds__(256, 4) void k_agg(const float* __restrict__ adj,
                                                const _Float16* __restrict__ zT,
                                                const float* __restrict__ dinv,
                                                float* __restrict__ out) {
    __shared__ __align__(16) _Float16 SA0[64 * 64], SA1[64 * 64];
    __shared__ __align__(16) _Float16 SZ0[64 * 64], SZ1[64 * 64];
    const int t = threadIdx.x;
    const int bb = blockIdx.y;
    const int i0 = blockIdx.x << 6;
    const int w = t >> 6, lane = t & 63;
    const int lr = lane & 15, lg = lane >> 4;
    const float* dvB = dinv + bb * NN;
    const int r0 = t >> 3, c0 = t & 7;               // staging rows 0..31
    const int r1 = 32 + (t >> 3);                    // staging rows 32..63

    f32x4 Aa00, Aa01, Aa10, Aa11;  h8 Az0, Az1;      // named prefetch set A
    f32x4 Ba00, Ba01, Ba10, Ba11;  h8 Bz0, Bz1;      // named prefetch set B

    const f32x4 zero = {0.f, 0.f, 0.f, 0.f};
    f32x4 acc[4];
#pragma unroll
    for (int nf = 0; nf < 4; ++nf) acc[nf] = zero;

    LOADT(A, 0);
    LOADT(B, 1);
    WRITET(A, 0, SA0, SZ0);
    BARNV();
#pragma unroll 1
    for (int kt = 0; kt < 16; kt += 2) {
        if (kt + 2 < 16) LOADT(A, kt + 2);           // in flight across barriers
        MMAT(SA0, SZ0);                              // tile kt
        WRITET(B, kt + 1, SA1, SZ1);
        BARNV();
        if (kt + 3 < 16) LOADT(B, kt + 3);
        MMAT(SA1, SZ1);                              // tile kt+1
        if (kt + 2 < 16) WRITET(A, kt + 2, SA0, SZ0);
        BARNV();
    }

    // epilogue: out = dinv_i * (acc + dinv_i * z_i[d]); 4 consecutive output rows.
    const int ib = i0 + w * 16 + lg * 4;
    const float4 dv = *(const float4*)&dvB[ib];
#pragma unroll
    for (int nf = 0; nf < 4; ++nf) {
        const int d = nf * 16 + lr;
        const h4 zv = *(const h4*)(zT + ((size_t)bb * DD + d) * NN + ib);
        float* op = out + ((size_t)bb * NN + ib) * DD + d;
        __builtin_nontemporal_store(dv.x * (acc[nf][0] + dv.x * (float)zv[0]), op + 0 * DD);
        __builtin_nontemporal_store(dv.y * (acc[nf][1] + dv.y * (float)zv[1]), op + 1 * DD);
        __builtin_nontemporal_store(dv.z * (acc[nf][2] + dv.z * (float)zv[2]), op + 2 * DD);
        __builtin_nontemporal_store(dv.w * (acc[nf][3] + dv.w * (float)zv[3]), op + 3 * DD);
    }
}

extern "C" void kernel_launch(void* const* d_in, const int* in_sizes, int n_in,
                              void* d_out, int out_size, void* d_ws, size_t ws_size,
                              hipStream_t stream) {
    const float* adj = (const float*)d_in[0];
    const float* att = (const float*)d_in[1];
    const float* wgt = (const float*)d_in[2];
    float* out = (float*)d_out;
    char* ws = (char*)d_ws;

    size_t off = 0;
    _Float16* zT  = (_Float16*)(ws + off); off += (size_t)BATCH * DD * NN * 2;  // 8 MiB
    float*    dinv = (float*)(ws + off);                                        // 256 KiB

    k_degxw<<<XWB + DEGB, 256, 0, stream>>>(adj, att, wgt, zT, dinv,
                                            out + (size_t)BATCH * NN * DD);
    k_agg<<<dim3(NN / 64, BATCH), 256, 0, stream>>>(adj, zT, dinv, out);
}